// Round 13
// baseline (2435.954 us; speedup 1.0000x reference)
//
#include <hip/hip_runtime.h>
#include <math.h>

// GPT-2 small forward: B=2, T=1024, D=768, H=12, HD=64, L=12, V=50257
#define Bsz  2
#define Tlen 1024
#define Dm   768
#define Hh   12
#define HDm  64
#define Ll   12
#define Vv   50257
#define Mrows (Bsz * Tlen)
#define WPL  7077888   // shorts per layer of converted weights

typedef __attribute__((ext_vector_type(8))) short short8;
typedef __attribute__((ext_vector_type(4))) float f32x4;

__device__ __forceinline__ float bf2f(unsigned short u) {
  union { unsigned int i; float f; } v; v.i = ((unsigned int)u) << 16; return v.f;
}
__device__ __forceinline__ unsigned short f2bf(float f) {
  union { float f; unsigned int i; } v; v.f = f;
  unsigned int u = v.i;
  return (unsigned short)((u + 0x7FFFu + ((u >> 16) & 1u)) >> 16);  // RNE
}
__device__ __forceinline__ float gelu_f(float x) {
  const float c = 0.7978845608028654f; // sqrt(2/pi)
  return 0.5f * x * (1.0f + tanhf(c * (x + 0.044715f * x * x * x)));
}

// async global->LDS, 16B per lane. LDS dest must be wave-uniform base; HW adds lane*16.
__device__ __forceinline__ void gl_lds16(const unsigned short* g, unsigned short* l) {
  __builtin_amdgcn_global_load_lds(
      (const __attribute__((address_space(1))) unsigned int*)g,
      (__attribute__((address_space(3))) unsigned int*)l, 16, 0, 0);
}

// T2 slot-swap swizzle for [rows][32] bf16 tiles: physical slot p at row r holds
// logical k-slot p ^ ((r>>1)&3). Stage: lane l global k-slot = (l&3)^((l>>3)&3).
// Read logical fq at row fr: physical = fq ^ ((fr>>1)&3). Conflicts: 0 (verified r7).

// ---------------- embedding ----------------
__global__ void embed_kernel(const int* __restrict__ idx, const float* __restrict__ wte,
                             const float* __restrict__ wpe, float* __restrict__ x) {
  int i = (blockIdx.x * 256 + threadIdx.x) * 4;
  int d = i % Dm;
  int bt = i / Dm;
  int t = bt % Tlen;
  int tok = idx[bt];
  float4 a = *(const float4*)(wte + (size_t)tok * Dm + d);
  float4 p = *(const float4*)(wpe + (size_t)t * Dm + d);
  float4 r; r.x = a.x + p.x; r.y = a.y + p.y; r.z = a.z + p.z; r.w = a.w + p.w;
  *(float4*)(x + i) = r;
}

// ---------------- layernorm: wave-per-row, 4 rows/block ----------------
__global__ __launch_bounds__(256) void ln_wave(const float* __restrict__ x,
                                               const float* __restrict__ w,
                                               const float* __restrict__ b,
                                               unsigned short* __restrict__ out) {
  int tid = threadIdx.x, wv = tid >> 6, l = tid & 63;
  int row = blockIdx.x * 4 + wv;
  const float* xr = x + (size_t)row * Dm;
  float4 v[3];
  float s = 0.f, s2 = 0.f;
#pragma unroll
  for (int i = 0; i < 3; ++i) {
    v[i] = *(const float4*)(xr + l * 4 + i * 256);
    s += v[i].x + v[i].y + v[i].z + v[i].w;
    s2 += v[i].x * v[i].x + v[i].y * v[i].y + v[i].z * v[i].z + v[i].w * v[i].w;
  }
#pragma unroll
  for (int o = 1; o < 64; o <<= 1) {
    s += __shfl_xor(s, o, 64);
    s2 += __shfl_xor(s2, o, 64);
  }
  float mu = s * (1.0f / Dm);
  float var = s2 * (1.0f / Dm) - mu * mu;
  float rstd = rsqrtf(var + 1e-5f);
  unsigned short* yr = out + (size_t)row * Dm;
#pragma unroll
  for (int i = 0; i < 3; ++i) {
    float4 wv4 = *(const float4*)(w + l * 4 + i * 256);
    float4 bv4 = *(const float4*)(b + l * 4 + i * 256);
    ushort4 o4;
    o4.x = f2bf((v[i].x - mu) * rstd * wv4.x + bv4.x);
    o4.y = f2bf((v[i].y - mu) * rstd * wv4.y + bv4.y);
    o4.z = f2bf((v[i].z - mu) * rstd * wv4.z + bv4.z);
    o4.w = f2bf((v[i].w - mu) * rstd * wv4.w + bv4.w);
    *(ushort4*)(yr + l * 4 + i * 256) = o4;
  }
}

// ---------------- generic transpose-convert (lm_head chunks; zero-pads n >= nValid) ----------------
__global__ __launch_bounds__(256) void tconv_kernel(const float* __restrict__ W, int ldw,
                                                    int nValid, unsigned short* __restrict__ WT,
                                                    int K) {
  __shared__ float S[32][33];
  int n0 = blockIdx.x * 32, k0 = blockIdx.y * 32;
  int t = threadIdx.x;
  int nc = t & 31, kr0 = t >> 5;
#pragma unroll
  for (int i = 0; i < 4; ++i) {
    int kr = kr0 + i * 8;
    S[kr][nc] = (n0 + nc < nValid) ? W[(size_t)(k0 + kr) * ldw + n0 + nc] : 0.f;
  }
  __syncthreads();
  int r = t >> 3, c4 = (t & 7) * 4;
  ushort4 o;
  o.x = f2bf(S[c4 + 0][r]); o.y = f2bf(S[c4 + 1][r]);
  o.z = f2bf(S[c4 + 2][r]); o.w = f2bf(S[c4 + 3][r]);
  *(ushort4*)(WT + (size_t)(n0 + r) * K + k0 + c4) = o;
}

// ---------------- ALL-layer transpose-convert: 12 layers x 4 mats, ONE dispatch ----------------
__global__ __launch_bounds__(256) void tconv12_kernel(
    const float* __restrict__ attn_w, const float* __restrict__ proj_w,
    const float* __restrict__ fc_w, const float* __restrict__ fc2_w,
    unsigned short* __restrict__ wAll) {
  int bid = blockIdx.x;
  int lyr = bid / 6912, rem = bid % 6912;
  unsigned short* wL = wAll + (size_t)lyr * WPL;
  const float* W; unsigned short* WT; int ldw, K, ntn, local;
  if (rem < 1728)      { W = attn_w + (size_t)lyr * Dm * 3 * Dm; WT = wL;                     ldw = 2304; K = 768;  ntn = 72; local = rem; }
  else if (rem < 2304) { W = proj_w + (size_t)lyr * Dm * Dm;     WT = wL + 1769472;           ldw = 768;  K = 768;  ntn = 24; local = rem - 1728; }
  else if (rem < 4608) { W = fc_w + (size_t)lyr * Dm * 4 * Dm;   WT = wL + 1769472 + 589824;  ldw = 3072; K = 768;  ntn = 96; local = rem - 2304; }
  else                 { W = fc2_w + (size_t)lyr * 4 * Dm * Dm;  WT = wL + 1769472 + 589824 + 2359296; ldw = 768; K = 3072; ntn = 24; local = rem - 4608; }
  int n0 = (local % ntn) * 32, k0 = (local / ntn) * 32;
  __shared__ float S[32][33];
  int t = threadIdx.x;
  int nc = t & 31, kr0 = t >> 5;
#pragma unroll
  for (int i = 0; i < 4; ++i) {
    int kr = kr0 + i * 8;
    S[kr][nc] = W[(size_t)(k0 + kr) * ldw + n0 + nc];
  }
  __syncthreads();
  int r = t >> 3, c4 = (t & 7) * 4;
  ushort4 o;
  o.x = f2bf(S[c4 + 0][r]); o.y = f2bf(S[c4 + 1][r]);
  o.z = f2bf(S[c4 + 2][r]); o.w = f2bf(S[c4 + 3][r]);
  *(ushort4*)(WT + (size_t)(n0 + r) * K + k0 + c4) = o;
}

// ---------------- lm_head GEMM: 128x256 tile, 2-phase dbuf, T2 swizzled, XCD-grouped ----------------
template<bool XMAP>
__global__ __launch_bounds__(256) void gemm_big256(
    const unsigned short* __restrict__ A, const unsigned short* __restrict__ B, int K,
    float* __restrict__ outF, int ldc, int nValid, int nColTiles) {
  int brow, bcol;
  if (XMAP) {
    int b = blockIdx.x, xcd = b & 7, slot = b >> 3;
    bcol = xcd + 8 * (slot >> 4);
    brow = slot & 15;
    if (bcol >= nColTiles) return;
  } else {
    bcol = blockIdx.x; brow = blockIdx.y;
  }
  __shared__ alignas(16) unsigned short As[2][128][32];
  __shared__ alignas(16) unsigned short Bs[2][256][32];
  int tid = threadIdx.x;
  int rowBase = brow * 128, colBase = bcol * 256;
  int w = tid >> 6, l = tid & 63;
  int wr = w >> 1, wc = w & 1;
  int srow = l >> 2;
  int skk = (((l & 3) ^ ((l >> 3) & 3))) * 8;
  const unsigned short* aSrc = A + (size_t)(rowBase + w * 16 + srow) * K + skk;
  const unsigned short* bSrc = B + (size_t)(colBase + w * 16 + srow) * K + skk;

  f32x4 acc[4][8];
#pragma unroll
  for (int m = 0; m < 4; ++m)
#pragma unroll
    for (int n = 0; n < 8; ++n) acc[m][n] = (f32x4){0.f, 0.f, 0.f, 0.f};

  int fr = l & 15, fq = l >> 4;
  int kslot = (fq ^ ((fr >> 1) & 3)) * 8;

#define STG256(k0_, buf_)                                                 \
  { gl_lds16(aSrc + (k0_), &As[buf_][w * 16][0]);                         \
    gl_lds16(aSrc + (size_t)64 * K + (k0_), &As[buf_][w * 16 + 64][0]);   \
    gl_lds16(bSrc + (k0_), &Bs[buf_][w * 16][0]);                         \
    gl_lds16(bSrc + (size_t)64 * K + (k0_), &Bs[buf_][w * 16 + 64][0]);   \
    gl_lds16(bSrc + (size_t)128 * K + (k0_), &Bs[buf_][w * 16 + 128][0]); \
    gl_lds16(bSrc + (size_t)192 * K + (k0_), &Bs[buf_][w * 16 + 192][0]); }

  int nIt = K >> 5;
  STG256(0, 0);
  for (int it = 0; it < nIt; ++it) {
    int cur = it & 1;
    int k0 = it * 32;
    if (it + 1 < nIt) {
      STG256(k0 + 32, cur ^ 1);
      asm volatile("s_waitcnt vmcnt(6)" ::: "memory");
    } else {
      asm volatile("s_waitcnt vmcnt(0)" ::: "memory");
    }
    asm volatile("s_barrier" ::: "memory");

    short8 af[4], bfr[8];
#pragma unroll
    for (int m = 0; m < 4; ++m)
      af[m] = *(const short8*)&As[cur][wr * 64 + m * 16 + fr][kslot];
#pragma unroll
    for (int n = 0; n < 8; ++n)
      bfr[n] = *(const short8*)&Bs[cur][wc * 128 + n * 16 + fr][kslot];
    __builtin_amdgcn_s_setprio(1);
#pragma unroll
    for (int m = 0; m < 4; ++m)
#pragma unroll
      for (int n = 0; n < 8; ++n)
        acc[m][n] = __builtin_amdgcn_mfma_f32_16x16x32_bf16(af[m], bfr[n], acc[m][n], 0, 0, 0);
    __builtin_amdgcn_s_setprio(0);
    asm volatile("s_barrier" ::: "memory");
  }
#undef STG256

#pragma unroll
  for (int m = 0; m < 4; ++m) {
    int row = rowBase + wr * 64 + m * 16 + fq * 4;
#pragma unroll
    for (int n = 0; n < 8; ++n) {
      int col = colBase + wc * 128 + n * 16 + fr;
      if (col >= nValid) continue;
#pragma unroll
      for (int j = 0; j < 4; ++j)
        outF[(size_t)(row + j) * ldc + col] = acc[m][n][j];
    }
  }
}

// ---------------- bf16 MFMA GEMM, 64x128, 2-phase dbuf, T2 swizzled, XCD-grouped (trunk) ----------------
// 1D grid = 8 * 32 * ceil(nct/8); all 32 row-blocks of a B col-panel land on one XCD.
__global__ __launch_bounds__(256) void gemm_bf16_sm(
    const unsigned short* __restrict__ A, const unsigned short* __restrict__ B, int K,
    const float* __restrict__ bias,
    float* __restrict__ outF, unsigned short* __restrict__ outB,
    int ldc, int act, int nColTiles) {
  int bidx = blockIdx.x, xcd = bidx & 7, slot = bidx >> 3;
  int rowT = slot & 31;
  int colT = xcd + 8 * (slot >> 5);
  if (colT >= nColTiles) return;
  __shared__ alignas(16) unsigned short As[2][64][32];
  __shared__ alignas(16) unsigned short Bs[2][128][32];
  int tid = threadIdx.x;
  int rowBase = rowT * 64;
  int colBase = colT * 128;
  int w = tid >> 6, l = tid & 63;
  int fr = l & 15, fq = l >> 4;

  int srow = l >> 2;
  int skk = (((l & 3) ^ ((l >> 3) & 3))) * 8;
  const unsigned short* aSrc = A + (size_t)(rowBase + w * 16 + srow) * K + skk;
  const unsigned short* bSrc = B + (size_t)(colBase + w * 16 + srow) * K + skk;
  int kslot = (fq ^ ((fr >> 1) & 3)) * 8;

  f32x4 acc[4][2];
#pragma unroll
  for (int m = 0; m < 4; ++m)
#pragma unroll
    for (int n = 0; n < 2; ++n) acc[m][n] = (f32x4){0.f, 0.f, 0.f, 0.f};

  gl_lds16(aSrc, &As[0][w * 16][0]);
  gl_lds16(bSrc, &Bs[0][w * 16][0]);
  gl_lds16(bSrc + (size_t)64 * K, &Bs[0][w * 16 + 64][0]);

  int nIt = K >> 5;
  for (int it = 0; it < nIt; ++it) {
    int cur = it & 1;
    int k0 = it * 32;
    if (it + 1 < nIt) {
      int nx = cur ^ 1;
      gl_lds16(aSrc + k0 + 32, &As[nx][w * 16][0]);
      gl_lds16(bSrc + k0 + 32, &Bs[nx][w * 16][0]);
      gl_lds16(bSrc + (size_t)64 * K + k0 + 32, &Bs[nx][w * 16 + 64][0]);
      asm volatile("s_waitcnt vmcnt(3)" ::: "memory");
    } else {
      asm volatile("s_waitcnt vmcnt(0)" ::: "memory");
    }
    asm volatile("s_barrier" ::: "memory");

    short8 af[4], bfr[2];
#pragma unroll
    for (int m = 0; m < 4; ++m)
      af[m] = *(const short8*)&As[cur][m * 16 + fr][kslot];
#pragma unroll
    for (int n = 0; n < 2; ++n)
      bfr[n] = *(const short8*)&Bs[cur][w * 32 + n * 16 + fr][kslot];
#pragma unroll
    for (int m = 0; m < 4; ++m)
#pragma unroll
      for (int n = 0; n < 2; ++n)
        acc[m][n] = __builtin_amdgcn_mfma_f32_16x16x32_bf16(af[m], bfr[n], acc[m][n], 0, 0, 0);
    asm volatile("s_barrier" ::: "memory");
  }

#pragma unroll
  for (int m = 0; m < 4; ++m) {
    int row = rowBase + m * 16 + fq * 4;
#pragma unroll
    for (int n = 0; n < 2; ++n) {
      int col = colBase + w * 32 + n * 16 + fr;
      float bv = bias ? bias[col] : 0.f;
#pragma unroll
      for (int j = 0; j < 4; ++j) {
        float v = acc[m][n][j] + bv;
        if (act) v = gelu_f(v);
        if (outF) outF[(size_t)(row + j) * ldc + col] = v;
        else      outB[(size_t)(row + j) * ldc + col] = f2bf(v);
      }
    }
  }
}

// ---------------- split-K residual GEMM, 2-phase dbuf, XCD-grouped: atomics into fp32 x ----------------
// blockIdx.x = XMAP(col,row); blockIdx.y = k-split index.
__global__ __launch_bounds__(256) void gemm_splitk(
    const unsigned short* __restrict__ A, const unsigned short* __restrict__ B, int K,
    int Klen, const float* __restrict__ bias, float* __restrict__ outF, int ldc,
    int nColTiles) {
  int bidx = blockIdx.x, xcd = bidx & 7, slot = bidx >> 3;
  int rowT = slot & 31;
  int colT = xcd + 8 * (slot >> 5);
  if (colT >= nColTiles) return;
  __shared__ alignas(16) unsigned short As[2][64][32];
  __shared__ alignas(16) unsigned short Bs[2][128][32];
  int tid = threadIdx.x;
  int rowBase = rowT * 64;
  int colBase = colT * 128;
  int Koff = blockIdx.y * Klen;
  int w = tid >> 6, l = tid & 63;
  int fr = l & 15, fq = l >> 4;

  int srow = l >> 2;
  int skk = (((l & 3) ^ ((l >> 3) & 3))) * 8;
  const unsigned short* aSrc = A + (size_t)(rowBase + w * 16 + srow) * K + Koff + skk;
  const unsigned short* bSrc = B + (size_t)(colBase + w * 16 + srow) * K + Koff + skk;
  int kslot = (fq ^ ((fr >> 1) & 3)) * 8;

  f32x4 acc[4][2];
#pragma unroll
  for (int m = 0; m < 4; ++m)
#pragma unroll
    for (int n = 0; n < 2; ++n) acc[m][n] = (f32x4){0.f, 0.f, 0.f, 0.f};

  gl_lds16(aSrc, &As[0][w * 16][0]);
  gl_lds16(bSrc, &Bs[0][w * 16][0]);
  gl_lds16(bSrc + (size_t)64 * K, &Bs[0][w * 16 + 64][0]);

  int nIt = Klen >> 5;
  for (int it = 0; it < nIt; ++it) {
    int cur = it & 1;
    int k0 = it * 32;
    if (it + 1 < nIt) {
      int nx = cur ^ 1;
      gl_lds16(aSrc + k0 + 32, &As[nx][w * 16][0]);
      gl_lds16(bSrc + k0 + 32, &Bs[nx][w * 16][0]);
      gl_lds16(bSrc + (size_t)64 * K + k0 + 32, &Bs[nx][w * 16 + 64][0]);
      asm volatile("s_waitcnt vmcnt(3)" ::: "memory");
    } else {
      asm volatile("s_waitcnt vmcnt(0)" ::: "memory");
    }
    asm volatile("s_barrier" ::: "memory");

    short8 af[4], bfr[2];
#pragma unroll
    for (int m = 0; m < 4; ++m)
      af[m] = *(const short8*)&As[cur][m * 16 + fr][kslot];
#pragma unroll
    for (int n = 0; n < 2; ++n)
      bfr[n] = *(const short8*)&Bs[cur][w * 32 + n * 16 + fr][kslot];
#pragma unroll
    for (int m = 0; m < 4; ++m)
#pragma unroll
      for (int n = 0; n < 2; ++n)
        acc[m][n] = __builtin_amdgcn_mfma_f32_16x16x32_bf16(af[m], bfr[n], acc[m][n], 0, 0, 0);
    asm volatile("s_barrier" ::: "memory");
  }

  bool addBias = (blockIdx.y == 0);
#pragma unroll
  for (int m = 0; m < 4; ++m) {
    int row = rowBase + m * 16 + fq * 4;
#pragma unroll
    for (int n = 0; n < 2; ++n) {
      int col = colBase + w * 32 + n * 16 + fr;
      float bv = addBias ? bias[col] : 0.f;
#pragma unroll
      for (int j = 0; j < 4; ++j) {
        unsafeAtomicAdd(&outF[(size_t)(row + j) * ldc + col], acc[m][n][j] + bv);
      }
    }
  }
}

// ---------------- MFMA flash attention: 128 thr / 2 waves, QBLK=32, LPT order, setprio ----------------
__global__ __launch_bounds__(128) void attn_mfma(const unsigned short* __restrict__ qkv,
                                                 unsigned short* __restrict__ y) {
  int bx = blockIdx.x;
  int qt = 31 - (bx / 24);
  int bh = bx % 24;
  int h  = bh % Hh;
  int b  = bh / Hh;
  int q0 = qt * 32;
  int tid = threadIdx.x;             // 0..127
  int w = tid >> 6, l = tid & 63;
  int g = l >> 4, fr = l & 15;

  __shared__ alignas(16) unsigned short Kl[2][4096];
  __shared__ alignas(16) unsigned short Vt[4096];
  __shared__ alignas(16) unsigned short Pl[2][1024];

  const size_t rs = 3 * Dm;
  const unsigned short* base = qkv + (size_t)(b * Tlen) * rs + h * HDm;

  short8 qf[2];
  {
    const unsigned short* qrow = base + (size_t)(q0 + w * 16 + fr) * rs;
    qf[0] = *(const short8*)(qrow + g * 8);
    qf[1] = *(const short8*)(qrow + g * 8 + 32);
  }

  int vt_t = tid >> 1;
  int vt_d0 = (tid & 1) * 2;
  uint4 v0r, v1r, v2r, v3r;

  f32x4 oAcc[4];
#pragma unroll
  for (int nd = 0; nd < 4; ++nd) oAcc[nd] = (f32x4){0.f, 0.f, 0.f, 0.f};
  float mRun[4] = {-1e30f, -1e30f, -1e30f, -1e30f};
  float lRun[4] = {0.f, 0.f, 0.f, 0.f};

  unsigned short* Pw = &Pl[w][0];
  int nkt = qt / 2 + 1;

#define STAGE_K(kb_, buf_)                                                \
  { _Pragma("unroll")                                                     \
    for (int i = 0; i < 4; ++i) {                                         \
      int c = i * 128 + tid;                                              \
      int t = c >> 3, cl = c & 7;                                         \
      int dch = cl ^ (t & 7);                                             \
      gl_lds16(base + (size_t)((kb_) + t) * rs + Dm + dch * 8,            \
               &Kl[buf_][(i * 128 + w * 64) * 8]);                        \
    } }

#define LOAD_V(kb_)                                                       \
  { const unsigned short* p = base + (size_t)((kb_) + vt_t) * rs + 2 * Dm + vt_d0 * 16; \
    v0r = *(const uint4*)p;  v1r = *(const uint4*)(p + 8);                \
    v2r = *(const uint4*)(p + 16); v3r = *(const uint4*)(p + 24); }

  STAGE_K(0, 0);
  LOAD_V(0);

  for (int kt = 0; kt < nkt; ++kt) {
    int cur = kt & 1;
    int kbase = kt * 64;
    asm volatile("s_waitcnt vmcnt(0)" ::: "memory");
    __builtin_amdgcn_s_barrier();

    {
      union { uint4 u; unsigned short s[8]; } a, bb, cc, dd;
      a.u = v0r; bb.u = v1r; cc.u = v2r; dd.u = v3r;
#pragma unroll
      for (int j = 0; j < 8; ++j) {
        int d = vt_d0 * 16 + j;
        Vt[d * 64 + (vt_t ^ ((d & 7) << 3))] = a.s[j];
        int d2 = d + 8;
        Vt[d2 * 64 + (vt_t ^ ((d2 & 7) << 3))] = bb.s[j];
        int d3 = d + 16;
        Vt[d3 * 64 + (vt_t ^ ((d3 & 7) << 3))] = cc.s[j];
        int d4 = d + 24;
        Vt[d4 * 64 + (vt_t ^ ((d4 & 7) << 3))] = dd.s[j];
      }
    }
    if (kt + 1 < nkt) {
      int kb = kbase + 64;
      STAGE_K(kb, cur ^ 1);
      LOAD_V(kb);
    }
    asm volatile("s_waitcnt lgkmcnt(0)" ::: "memory");
    __builtin_amdgcn_s_barrier();

    // ---- QK^T ----
    f32x4 sAcc[4];
#pragma unroll
    for (int nt = 0; nt < 4; ++nt) sAcc[nt] = (f32x4){0.f, 0.f, 0.f, 0.f};
    __builtin_amdgcn_s_setprio(1);
#pragma unroll
    for (int ks = 0; ks < 2; ++ks)
#pragma unroll
      for (int nt = 0; nt < 4; ++nt) {
        int kcol = nt * 16 + fr;
        short8 kf = *(const short8*)&Kl[cur][kcol * 64 + ((g * 8 + ks * 32) ^ ((kcol & 7) << 3))];
        sAcc[nt] = __builtin_amdgcn_mfma_f32_16x16x32_bf16(qf[ks], kf, sAcc[nt], 0, 0, 0);
      }
    __builtin_amdgcn_s_setprio(0);

    // ---- online softmax ----
    float corr[4];
#pragma unroll
    for (int j = 0; j < 4; ++j) {
      int qg = q0 + w * 16 + g * 4 + j;
      float tm = -1e30f;
#pragma unroll
      for (int nt = 0; nt < 4; ++nt) {
        float s = sAcc[nt][j] * 0.125f;
        int tg = kbase + nt * 16 + fr;
        if (tg > qg) s = -1e30f;
        sAcc[nt][j] = s;
        tm = fmaxf(tm, s);
      }
      tm = fmaxf(tm, __shfl_xor(tm, 1, 16));
      tm = fmaxf(tm, __shfl_xor(tm, 2, 16));
      tm = fmaxf(tm, __shfl_xor(tm, 4, 16));
      tm = fmaxf(tm, __shfl_xor(tm, 8, 16));
      float mN = fmaxf(mRun[j], tm);
      corr[j] = __expf(mRun[j] - mN);
      mRun[j] = mN;
      float ps = 0.f;
#pragma unroll
      for (int nt = 0; nt < 4; ++nt) {
        float p = __expf(sAcc[nt][j] - mN);
        sAcc[nt][j] = p;
        ps += p;
      }
      ps += __shfl_xor(ps, 1, 16);
      ps += __shfl_xor(ps, 2, 16);
      ps += __shfl_xor(ps, 4, 16);
      ps += __shfl_xor(ps, 8, 16);
      lRun[j] = lRun[j] * corr[j] + ps;
    }

#pragma unroll
    for (int nt = 0; nt < 4; ++nt)
#pragma unroll
      for (int j = 0; j < 4; ++j) {
        int q = g * 4 + j;
        int t = nt * 16 + fr;
        Pw[q * 64 + (t ^ ((q & 7) << 3))] = f2bf(sAcc[nt][j]);
      }
#pragma unroll
    for (int nd = 0; nd < 4; ++nd)
#pragma unroll
      for (int j = 0; j < 4; ++j) oAcc[nd][j] *= corr[j];

    // ---- PV ----
    __builtin_amdgcn_s_setprio(1);
#pragma unroll
    for (int ks = 0; ks < 2; ++ks) {
      short8 pf = *(const short8*)&Pw[fr * 64 + ((g * 8 + ks * 32) ^ ((fr & 7) << 3))];
#pragma unroll
      for (int nd = 0; nd < 4; ++nd) {
        int d = nd * 16 + fr;
        short8 vf = *(const short8*)&Vt[d * 64 + ((g * 8 + ks * 32) ^ ((fr & 7) << 3))];
        oAcc[nd] = __builtin_amdgcn_mfma_f32_16x16x32_bf16(pf, vf, oAcc[nd], 0, 0, 0);
      }
    }
    __builtin_amdgcn_s_setprio(0);
  }
#undef STAGE_K
#undef LOAD_V

#pragma unroll
  for (int j = 0; j < 4; ++j) {
    float inv = 1.0f / lRun[j];
    int q = q0 + w * 16 + g * 4 + j;
    unsigned short* yr = y + (size_t)(b * Tlen + q) * Dm + h * HDm + fr;
#pragma unroll
    for (int nd = 0; nd < 4; ++nd)
      yr[nd * 16] = f2bf(oAcc[nd][j] * inv);
  }
}

extern "C" void kernel_launch(void* const* d_in, const int* in_sizes, int n_in,
                              void* d_out, int out_size, void* d_ws, size_t ws_size,
                              hipStream_t stream) {
  const int*   idx    = (const int*)d_in[0];
  const float* wte    = (const float*)d_in[1];
  const float* wpe    = (const float*)d_in[2];
  const float* ln1_w  = (const float*)d_in[3];
  const float* ln1_b  = (const float*)d_in[4];
  const float* attn_w = (const float*)d_in[5];
  const float* attn_b = (const float*)d_in[6];
  const float* proj_w = (const float*)d_in[7];
  const float* proj_b = (const float*)d_in[8];
  const float* ln2_w  = (const float*)d_in[9];
  const float* ln2_b  = (const float*)d_in[10];
  const float* fc_w   = (const float*)d_in[11];
  const float* fc_b   = (const float*)d_in[12];
  const float* fc2_w  = (const float*)d_in[13];
  const float* fc2_b  = (const float*)d_in[14];
  const float* lnf_w  = (const float*)d_in[15];
  const float* lnf_b  = (const float*)d_in[16];
  const float* lmw    = (const float*)d_in[17];
  float* out = (float*)d_out;

  float* x = (float*)d_ws;                                    // [M][768] fp32
  unsigned short* qkvb = (unsigned short*)(x + (size_t)Mrows * Dm);   // [M][2304] bf16
  unsigned short* xb   = qkvb + (size_t)Mrows * 3 * Dm;       // [M][768] bf16
  unsigned short* yb   = xb + (size_t)Mrows * Dm;             // [M][768] bf16
  unsigned short* mb   = yb + (size_t)Mrows * Dm;             // [M][3072] bf16
  unsigned short* wbuf = mb + (size_t)Mrows * 4 * Dm;         // lm_head chunk weights

  // d_out as scratch for trunk weights (170MB < 412MB); logits fully overwrite later.
  unsigned short* wAll = (unsigned short*)d_out;

  const size_t baseBytes = (size_t)Mrows * Dm * 4 + (size_t)Mrows * 9 * Dm * 2;  // 34.6MB
  size_t availShorts = (ws_size - baseBytes) / 2;
  long long maxRows = (long long)(availShorts / Dm);
  long long cc = (maxRows - 256) & ~255LL;
  if (cc > Vv) cc = Vv;
  const int chunkCols = (int)cc;

  embed_kernel<<<(Mrows * Dm) / 1024, 256, 0, stream>>>(idx, wte, wpe, x);
  tconv12_kernel<<<6912 * Ll, 256, 0, stream>>>(attn_w, proj_w, fc_w, fc2_w, wAll);

  for (int l = 0; l < Ll; ++l) {
    unsigned short* wL    = wAll + (size_t)l * WPL;
    unsigned short* wAttn = wL;                       // [2304][768]
    unsigned short* wProj = wL + 1769472;             // [768][768]
    unsigned short* wFc   = wL + 1769472 + 589824;    // [3072][768]
    unsigned short* wFc2  = wL + 1769472 + 589824 + 2359296;  // [768][3072]

    ln_wave<<<Mrows / 4, 256, 0, stream>>>(x, ln1_w + l * Dm, ln1_b + l * Dm, xb);
    // qkv: nct=18 -> XMAP grid 8*32*3 = 768 (guarded)
    gemm_bf16_sm<<<768, 256, 0, stream>>>(xb, wAttn, Dm, attn_b + (size_t)l * 3 * Dm,
                                          nullptr, qkvb, 3 * Dm, 0, 18);
    attn_mfma<<<24 * 32, 128, 0, stream>>>(qkvb, yb);
    // proj: nct=6 -> XMAP grid 8*32 = 256 (guarded), z=2 in blockIdx.y
    gemm_splitk<<<dim3(256, 2), 256, 0, stream>>>(yb, wProj, Dm, Dm / 2,
                                                  proj_b + (size_t)l * Dm, x, Dm, 6);
    ln_wave<<<Mrows / 4, 256, 0, stream>>>(x, ln2_w + l * Dm, ln2_b + l * Dm, xb);
    // fc: nct=24 -> XMAP grid 8*32*3 = 768 (exact)
    gemm_bf16_sm<<<768, 256, 0, stream>>>(xb, wFc, Dm, fc_b + (size_t)l * 4 * Dm,
                                          nullptr, mb, 4 * Dm, 1, 24);
    gemm_splitk<<<dim3(256, 2), 256, 0, stream>>>(mb, wFc2, 4 * Dm, 2 * Dm,
                                                  fc2_b + (size_t)l * Dm, x, Dm, 6);
  }

  ln_wave<<<Mrows / 4, 256, 0, stream>>>(x, lnf_w, lnf_b, xb);
  for (int base = 0; base < Vv; base += chunkCols) {
    int ncv = Vv - base; if (ncv > chunkCols) ncv = chunkCols;
    int ntiles = (ncv + 255) / 256;
    tconv_kernel<<<dim3(ntiles * 8, 24), 256, 0, stream>>>(lmw + base, Vv, ncv, wbuf, Dm);
    int cpx = (ntiles + 7) / 8;
    gemm_big256<true><<<8 * 16 * cpx, 256, 0, stream>>>(
        xb, wbuf, Dm, out + base, Vv, ncv, ntiles);
  }
}

// Round 14
// 2140.943 us; speedup vs baseline: 1.1378x; 1.1378x over previous
//
#include <hip/hip_runtime.h>
#include <math.h>

// GPT-2 small forward: B=2, T=1024, D=768, H=12, HD=64, L=12, V=50257
#define Bsz  2
#define Tlen 1024
#define Dm   768
#define Hh   12
#define HDm  64
#define Ll   12
#define Vv   50257
#define Mrows (Bsz * Tlen)

typedef __attribute__((ext_vector_type(8))) short short8;
typedef __attribute__((ext_vector_type(4))) float f32x4;

__device__ __forceinline__ float bf2f(unsigned short u) {
  union { unsigned int i; float f; } v; v.i = ((unsigned int)u) << 16; return v.f;
}
__device__ __forceinline__ unsigned short f2bf(float f) {
  union { float f; unsigned int i; } v; v.f = f;
  unsigned int u = v.i;
  return (unsigned short)((u + 0x7FFFu + ((u >> 16) & 1u)) >> 16);  // RNE
}
__device__ __forceinline__ float gelu_f(float x) {
  const float c = 0.7978845608028654f; // sqrt(2/pi)
  return 0.5f * x * (1.0f + tanhf(c * (x + 0.044715f * x * x * x)));
}

// async global->LDS, 16B per lane. LDS dest must be wave-uniform base; HW adds lane*16.
__device__ __forceinline__ void gl_lds16(const unsigned short* g, unsigned short* l) {
  __builtin_amdgcn_global_load_lds(
      (const __attribute__((address_space(1))) unsigned int*)g,
      (__attribute__((address_space(3))) unsigned int*)l, 16, 0, 0);
}

// T2 slot-swap swizzle for [rows][32] bf16 tiles: physical slot p at row r holds
// logical k-slot p ^ ((r>>1)&3). Stage: lane l global k-slot = (l&3)^((l>>3)&3).
// Read logical fq at row fr: physical = fq ^ ((fr>>1)&3). Conflicts: 0 (verified r7).

// ---------------- embedding ----------------
__global__ void embed_kernel(const int* __restrict__ idx, const float* __restrict__ wte,
                             const float* __restrict__ wpe, float* __restrict__ x) {
  int i = (blockIdx.x * 256 + threadIdx.x) * 4;
  int d = i % Dm;
  int bt = i / Dm;
  int t = bt % Tlen;
  int tok = idx[bt];
  float4 a = *(const float4*)(wte + (size_t)tok * Dm + d);
  float4 p = *(const float4*)(wpe + (size_t)t * Dm + d);
  float4 r; r.x = a.x + p.x; r.y = a.y + p.y; r.z = a.z + p.z; r.w = a.w + p.w;
  *(float4*)(x + i) = r;
}

// ---------------- layernorm: wave-per-row, 4 rows/block ----------------
__global__ __launch_bounds__(256) void ln_wave(const float* __restrict__ x,
                                               const float* __restrict__ w,
                                               const float* __restrict__ b,
                                               unsigned short* __restrict__ out) {
  int tid = threadIdx.x, wv = tid >> 6, l = tid & 63;
  int row = blockIdx.x * 4 + wv;
  const float* xr = x + (size_t)row * Dm;
  float4 v[3];
  float s = 0.f, s2 = 0.f;
#pragma unroll
  for (int i = 0; i < 3; ++i) {
    v[i] = *(const float4*)(xr + l * 4 + i * 256);
    s += v[i].x + v[i].y + v[i].z + v[i].w;
    s2 += v[i].x * v[i].x + v[i].y * v[i].y + v[i].z * v[i].z + v[i].w * v[i].w;
  }
#pragma unroll
  for (int o = 1; o < 64; o <<= 1) {
    s += __shfl_xor(s, o, 64);
    s2 += __shfl_xor(s2, o, 64);
  }
  float mu = s * (1.0f / Dm);
  float var = s2 * (1.0f / Dm) - mu * mu;
  float rstd = rsqrtf(var + 1e-5f);
  unsigned short* yr = out + (size_t)row * Dm;
#pragma unroll
  for (int i = 0; i < 3; ++i) {
    float4 wv4 = *(const float4*)(w + l * 4 + i * 256);
    float4 bv4 = *(const float4*)(b + l * 4 + i * 256);
    ushort4 o4;
    o4.x = f2bf((v[i].x - mu) * rstd * wv4.x + bv4.x);
    o4.y = f2bf((v[i].y - mu) * rstd * wv4.y + bv4.y);
    o4.z = f2bf((v[i].z - mu) * rstd * wv4.z + bv4.z);
    o4.w = f2bf((v[i].w - mu) * rstd * wv4.w + bv4.w);
    *(ushort4*)(yr + l * 4 + i * 256) = o4;
  }
}

// ---------------- generic transpose-convert (lm_head chunks; zero-pads n >= nValid) ----------------
__global__ __launch_bounds__(256) void tconv_kernel(const float* __restrict__ W, int ldw,
                                                    int nValid, unsigned short* __restrict__ WT,
                                                    int K) {
  __shared__ float S[32][33];
  int n0 = blockIdx.x * 32, k0 = blockIdx.y * 32;
  int t = threadIdx.x;
  int nc = t & 31, kr0 = t >> 5;
#pragma unroll
  for (int i = 0; i < 4; ++i) {
    int kr = kr0 + i * 8;
    S[kr][nc] = (n0 + nc < nValid) ? W[(size_t)(k0 + kr) * ldw + n0 + nc] : 0.f;
  }
  __syncthreads();
  int r = t >> 3, c4 = (t & 7) * 4;
  ushort4 o;
  o.x = f2bf(S[c4 + 0][r]); o.y = f2bf(S[c4 + 1][r]);
  o.z = f2bf(S[c4 + 2][r]); o.w = f2bf(S[c4 + 3][r]);
  *(ushort4*)(WT + (size_t)(n0 + r) * K + k0 + c4) = o;
}

// ---------------- batched per-layer transpose-convert: 4 weight mats, 1 dispatch ----------------
__global__ __launch_bounds__(256) void tconv4_kernel(
    const float* __restrict__ wA, const float* __restrict__ wP,
    const float* __restrict__ wF, const float* __restrict__ wF2,
    unsigned short* __restrict__ oA, unsigned short* __restrict__ oP,
    unsigned short* __restrict__ oF, unsigned short* __restrict__ oF2) {
  int bid = blockIdx.x;
  const float* W; unsigned short* WT; int ldw, K, ntn, local;
  if (bid < 1728)      { W = wA;  WT = oA;  ldw = 2304; K = 768;  ntn = 72; local = bid; }
  else if (bid < 2304) { W = wP;  WT = oP;  ldw = 768;  K = 768;  ntn = 24; local = bid - 1728; }
  else if (bid < 4608) { W = wF;  WT = oF;  ldw = 3072; K = 768;  ntn = 96; local = bid - 2304; }
  else                 { W = wF2; WT = oF2; ldw = 768;  K = 3072; ntn = 24; local = bid - 4608; }
  int n0 = (local % ntn) * 32, k0 = (local / ntn) * 32;
  __shared__ float S[32][33];
  int t = threadIdx.x;
  int nc = t & 31, kr0 = t >> 5;
#pragma unroll
  for (int i = 0; i < 4; ++i) {
    int kr = kr0 + i * 8;
    S[kr][nc] = W[(size_t)(k0 + kr) * ldw + n0 + nc];
  }
  __syncthreads();
  int r = t >> 3, c4 = (t & 7) * 4;
  ushort4 o;
  o.x = f2bf(S[c4 + 0][r]); o.y = f2bf(S[c4 + 1][r]);
  o.z = f2bf(S[c4 + 2][r]); o.w = f2bf(S[c4 + 3][r]);
  *(ushort4*)(WT + (size_t)(n0 + r) * K + k0 + c4) = o;
}

// ---------------- lm_head GEMM: 128x256 tile, 2-phase dbuf, T2 swizzled, XCD-grouped ----------------
// 4 waves 2x2; wave = 64 rows x 128 cols; acc[4][8]. (r10 version: 96 VGPR, 291us, no setprio)
template<bool XMAP>
__global__ __launch_bounds__(256) void gemm_big256(
    const unsigned short* __restrict__ A, const unsigned short* __restrict__ B, int K,
    float* __restrict__ outF, int ldc, int nValid, int nColTiles) {
  int brow, bcol;
  if (XMAP) {
    int b = blockIdx.x, xcd = b & 7, slot = b >> 3;
    bcol = xcd + 8 * (slot >> 4);
    brow = slot & 15;
    if (bcol >= nColTiles) return;
  } else {
    bcol = blockIdx.x; brow = blockIdx.y;
  }
  __shared__ alignas(16) unsigned short As[2][128][32];
  __shared__ alignas(16) unsigned short Bs[2][256][32];
  int tid = threadIdx.x;
  int rowBase = brow * 128, colBase = bcol * 256;
  int w = tid >> 6, l = tid & 63;
  int wr = w >> 1, wc = w & 1;
  int srow = l >> 2;
  int skk = (((l & 3) ^ ((l >> 3) & 3))) * 8;
  const unsigned short* aSrc = A + (size_t)(rowBase + w * 16 + srow) * K + skk;
  const unsigned short* bSrc = B + (size_t)(colBase + w * 16 + srow) * K + skk;

  f32x4 acc[4][8];
#pragma unroll
  for (int m = 0; m < 4; ++m)
#pragma unroll
    for (int n = 0; n < 8; ++n) acc[m][n] = (f32x4){0.f, 0.f, 0.f, 0.f};

  int fr = l & 15, fq = l >> 4;
  int kslot = (fq ^ ((fr >> 1) & 3)) * 8;

#define STG256(k0_, buf_)                                                 \
  { gl_lds16(aSrc + (k0_), &As[buf_][w * 16][0]);                         \
    gl_lds16(aSrc + (size_t)64 * K + (k0_), &As[buf_][w * 16 + 64][0]);   \
    gl_lds16(bSrc + (k0_), &Bs[buf_][w * 16][0]);                         \
    gl_lds16(bSrc + (size_t)64 * K + (k0_), &Bs[buf_][w * 16 + 64][0]);   \
    gl_lds16(bSrc + (size_t)128 * K + (k0_), &Bs[buf_][w * 16 + 128][0]); \
    gl_lds16(bSrc + (size_t)192 * K + (k0_), &Bs[buf_][w * 16 + 192][0]); }

  int nIt = K >> 5;
  STG256(0, 0);
  for (int it = 0; it < nIt; ++it) {
    int cur = it & 1;
    int k0 = it * 32;
    if (it + 1 < nIt) {
      STG256(k0 + 32, cur ^ 1);
      asm volatile("s_waitcnt vmcnt(6)" ::: "memory");   // tile `it` landed; 6 in flight
    } else {
      asm volatile("s_waitcnt vmcnt(0)" ::: "memory");
    }
    asm volatile("s_barrier" ::: "memory");

    short8 af[4], bfr[8];
#pragma unroll
    for (int m = 0; m < 4; ++m)
      af[m] = *(const short8*)&As[cur][wr * 64 + m * 16 + fr][kslot];
#pragma unroll
    for (int n = 0; n < 8; ++n)
      bfr[n] = *(const short8*)&Bs[cur][wc * 128 + n * 16 + fr][kslot];
#pragma unroll
    for (int m = 0; m < 4; ++m)
#pragma unroll
      for (int n = 0; n < 8; ++n)
        acc[m][n] = __builtin_amdgcn_mfma_f32_16x16x32_bf16(af[m], bfr[n], acc[m][n], 0, 0, 0);
    asm volatile("s_barrier" ::: "memory");
  }
#undef STG256

#pragma unroll
  for (int m = 0; m < 4; ++m) {
    int row = rowBase + wr * 64 + m * 16 + fq * 4;
#pragma unroll
    for (int n = 0; n < 8; ++n) {
      int col = colBase + wc * 128 + n * 16 + fr;
      if (col >= nValid) continue;
#pragma unroll
      for (int j = 0; j < 4; ++j)
        outF[(size_t)(row + j) * ldc + col] = acc[m][n][j];
    }
  }
}

// ---------------- bf16 MFMA GEMM, 64x128, 2-phase dbuf, T2 swizzled (trunk, r7-exact) ----------------
__global__ __launch_bounds__(256) void gemm_bf16_sm(
    const unsigned short* __restrict__ A, const unsigned short* __restrict__ B, int K,
    const float* __restrict__ bias,
    float* __restrict__ outF, unsigned short* __restrict__ outB,
    int ldc, int act) {
  __shared__ alignas(16) unsigned short As[2][64][32];
  __shared__ alignas(16) unsigned short Bs[2][128][32];
  int tid = threadIdx.x;
  int rowBase = blockIdx.y * 64;
  int colBase = blockIdx.x * 128;
  int w = tid >> 6, l = tid & 63;
  int fr = l & 15, fq = l >> 4;

  int srow = l >> 2;
  int skk = (((l & 3) ^ ((l >> 3) & 3))) * 8;
  const unsigned short* aSrc = A + (size_t)(rowBase + w * 16 + srow) * K + skk;
  const unsigned short* bSrc = B + (size_t)(colBase + w * 16 + srow) * K + skk;
  int kslot = (fq ^ ((fr >> 1) & 3)) * 8;

  f32x4 acc[4][2];
#pragma unroll
  for (int m = 0; m < 4; ++m)
#pragma unroll
    for (int n = 0; n < 2; ++n) acc[m][n] = (f32x4){0.f, 0.f, 0.f, 0.f};

  gl_lds16(aSrc, &As[0][w * 16][0]);
  gl_lds16(bSrc, &Bs[0][w * 16][0]);
  gl_lds16(bSrc + (size_t)64 * K, &Bs[0][w * 16 + 64][0]);

  int nIt = K >> 5;
  for (int it = 0; it < nIt; ++it) {
    int cur = it & 1;
    int k0 = it * 32;
    if (it + 1 < nIt) {
      int nx = cur ^ 1;
      gl_lds16(aSrc + k0 + 32, &As[nx][w * 16][0]);
      gl_lds16(bSrc + k0 + 32, &Bs[nx][w * 16][0]);
      gl_lds16(bSrc + (size_t)64 * K + k0 + 32, &Bs[nx][w * 16 + 64][0]);
      asm volatile("s_waitcnt vmcnt(3)" ::: "memory");
    } else {
      asm volatile("s_waitcnt vmcnt(0)" ::: "memory");
    }
    asm volatile("s_barrier" ::: "memory");

    short8 af[4], bfr[2];
#pragma unroll
    for (int m = 0; m < 4; ++m)
      af[m] = *(const short8*)&As[cur][m * 16 + fr][kslot];
#pragma unroll
    for (int n = 0; n < 2; ++n)
      bfr[n] = *(const short8*)&Bs[cur][w * 32 + n * 16 + fr][kslot];
#pragma unroll
    for (int m = 0; m < 4; ++m)
#pragma unroll
      for (int n = 0; n < 2; ++n)
        acc[m][n] = __builtin_amdgcn_mfma_f32_16x16x32_bf16(af[m], bfr[n], acc[m][n], 0, 0, 0);
    asm volatile("s_barrier" ::: "memory");
  }

#pragma unroll
  for (int m = 0; m < 4; ++m) {
    int row = rowBase + m * 16 + fq * 4;
#pragma unroll
    for (int n = 0; n < 2; ++n) {
      int col = colBase + w * 32 + n * 16 + fr;
      float bv = bias ? bias[col] : 0.f;
#pragma unroll
      for (int j = 0; j < 4; ++j) {
        float v = acc[m][n][j] + bv;
        if (act) v = gelu_f(v);
        if (outF) outF[(size_t)(row + j) * ldc + col] = v;
        else      outB[(size_t)(row + j) * ldc + col] = f2bf(v);
      }
    }
  }
}

// ---------------- split-K residual GEMM, 2-phase dbuf: atomics into fp32 x (r7-exact) ----------------
__global__ __launch_bounds__(256) void gemm_splitk(
    const unsigned short* __restrict__ A, const unsigned short* __restrict__ B, int K,
    int Klen, const float* __restrict__ bias, float* __restrict__ outF, int ldc) {
  __shared__ alignas(16) unsigned short As[2][64][32];
  __shared__ alignas(16) unsigned short Bs[2][128][32];
  int tid = threadIdx.x;
  int rowBase = blockIdx.y * 64;
  int colBase = blockIdx.x * 128;
  int Koff = blockIdx.z * Klen;
  int w = tid >> 6, l = tid & 63;
  int fr = l & 15, fq = l >> 4;

  int srow = l >> 2;
  int skk = (((l & 3) ^ ((l >> 3) & 3))) * 8;
  const unsigned short* aSrc = A + (size_t)(rowBase + w * 16 + srow) * K + Koff + skk;
  const unsigned short* bSrc = B + (size_t)(colBase + w * 16 + srow) * K + Koff + skk;
  int kslot = (fq ^ ((fr >> 1) & 3)) * 8;

  f32x4 acc[4][2];
#pragma unroll
  for (int m = 0; m < 4; ++m)
#pragma unroll
    for (int n = 0; n < 2; ++n) acc[m][n] = (f32x4){0.f, 0.f, 0.f, 0.f};

  gl_lds16(aSrc, &As[0][w * 16][0]);
  gl_lds16(bSrc, &Bs[0][w * 16][0]);
  gl_lds16(bSrc + (size_t)64 * K, &Bs[0][w * 16 + 64][0]);

  int nIt = Klen >> 5;
  for (int it = 0; it < nIt; ++it) {
    int cur = it & 1;
    int k0 = it * 32;
    if (it + 1 < nIt) {
      int nx = cur ^ 1;
      gl_lds16(aSrc + k0 + 32, &As[nx][w * 16][0]);
      gl_lds16(bSrc + k0 + 32, &Bs[nx][w * 16][0]);
      gl_lds16(bSrc + (size_t)64 * K + k0 + 32, &Bs[nx][w * 16 + 64][0]);
      asm volatile("s_waitcnt vmcnt(3)" ::: "memory");
    } else {
      asm volatile("s_waitcnt vmcnt(0)" ::: "memory");
    }
    asm volatile("s_barrier" ::: "memory");

    short8 af[4], bfr[2];
#pragma unroll
    for (int m = 0; m < 4; ++m)
      af[m] = *(const short8*)&As[cur][m * 16 + fr][kslot];
#pragma unroll
    for (int n = 0; n < 2; ++n)
      bfr[n] = *(const short8*)&Bs[cur][w * 32 + n * 16 + fr][kslot];
#pragma unroll
    for (int m = 0; m < 4; ++m)
#pragma unroll
      for (int n = 0; n < 2; ++n)
        acc[m][n] = __builtin_amdgcn_mfma_f32_16x16x32_bf16(af[m], bfr[n], acc[m][n], 0, 0, 0);
    asm volatile("s_barrier" ::: "memory");
  }

  bool addBias = (blockIdx.z == 0);
#pragma unroll
  for (int m = 0; m < 4; ++m) {
    int row = rowBase + m * 16 + fq * 4;
#pragma unroll
    for (int n = 0; n < 2; ++n) {
      int col = colBase + w * 32 + n * 16 + fr;
      float bv = addBias ? bias[col] : 0.f;
#pragma unroll
      for (int j = 0; j < 4; ++j) {
        unsafeAtomicAdd(&outF[(size_t)(row + j) * ldc + col], acc[m][n][j] + bv);
      }
    }
  }
}

// ---------------- MFMA flash attention (256 thr, LPT dispatch order, r7-exact) ----------------
__global__ __launch_bounds__(256) void attn_mfma(const unsigned short* __restrict__ qkv,
                                                 unsigned short* __restrict__ y) {
  int bx = blockIdx.x;
  int qt = 15 - (bx / 24);           // descending work: qt=15 blocks dispatch first
  int bh = bx % 24;
  int h  = bh % Hh;
  int b  = bh / Hh;
  int q0 = qt * 64;
  int tid = threadIdx.x;
  int w = tid >> 6, l = tid & 63;
  int g = l >> 4, fr = l & 15;

  __shared__ alignas(16) unsigned short Kl[2][4096];
  __shared__ alignas(16) unsigned short Vt[4096];
  __shared__ alignas(16) unsigned short Pl[4][1024];

  const size_t rs = 3 * Dm;
  const unsigned short* base = qkv + (size_t)(b * Tlen) * rs + h * HDm;

  short8 qf[2];
  {
    const unsigned short* qrow = base + (size_t)(q0 + w * 16 + fr) * rs;
    qf[0] = *(const short8*)(qrow + g * 8);
    qf[1] = *(const short8*)(qrow + g * 8 + 32);
  }

  int vt_t = tid >> 2, vt_dc = tid & 3;
  uint4 v0r, v1r;

  f32x4 oAcc[4];
#pragma unroll
  for (int nd = 0; nd < 4; ++nd) oAcc[nd] = (f32x4){0.f, 0.f, 0.f, 0.f};
  float mRun[4] = {-1e30f, -1e30f, -1e30f, -1e30f};
  float lRun[4] = {0.f, 0.f, 0.f, 0.f};

  unsigned short* Pw = &Pl[w][0];
  int nkt = qt + 1;

  {
#pragma unroll
    for (int i = 0; i < 2; ++i) {
      int c = i * 256 + tid;
      int t = c >> 3, cl = c & 7;
      int dch = cl ^ (t & 7);
      gl_lds16(base + (size_t)t * rs + Dm + dch * 8, &Kl[0][(i * 256 + w * 64) * 8]);
    }
    const unsigned short* p = base + (size_t)vt_t * rs + 2 * Dm + vt_dc * 16;
    v0r = *(const uint4*)p;
    v1r = *(const uint4*)(p + 8);
  }

  for (int kt = 0; kt < nkt; ++kt) {
    int cur = kt & 1;
    int kbase = kt * 64;
    asm volatile("s_waitcnt vmcnt(0)" ::: "memory");
    __builtin_amdgcn_s_barrier();

    {
      union { uint4 u; unsigned short s[8]; } a, bb;
      a.u = v0r; bb.u = v1r;
#pragma unroll
      for (int j = 0; j < 8; ++j) {
        int d = vt_dc * 16 + j;
        Vt[d * 64 + (vt_t ^ ((d & 7) << 3))] = a.s[j];
        int d2 = d + 8;
        Vt[d2 * 64 + (vt_t ^ ((d2 & 7) << 3))] = bb.s[j];
      }
    }
    if (kt + 1 < nkt) {
      int kb = kbase + 64;
#pragma unroll
      for (int i = 0; i < 2; ++i) {
        int c = i * 256 + tid;
        int t = c >> 3, cl = c & 7;
        int dch = cl ^ (t & 7);
        gl_lds16(base + (size_t)(kb + t) * rs + Dm + dch * 8,
                 &Kl[cur ^ 1][(i * 256 + w * 64) * 8]);
      }
      const unsigned short* p = base + (size_t)(kb + vt_t) * rs + 2 * Dm + vt_dc * 16;
      v0r = *(const uint4*)p;
      v1r = *(const uint4*)(p + 8);
    }
    asm volatile("s_waitcnt lgkmcnt(0)" ::: "memory");
    __builtin_amdgcn_s_barrier();

    f32x4 sAcc[4];
#pragma unroll
    for (int nt = 0; nt < 4; ++nt) sAcc[nt] = (f32x4){0.f, 0.f, 0.f, 0.f};
#pragma unroll
    for (int ks = 0; ks < 2; ++ks)
#pragma unroll
      for (int nt = 0; nt < 4; ++nt) {
        int kcol = nt * 16 + fr;
        short8 kf = *(const short8*)&Kl[cur][kcol * 64 + ((g * 8 + ks * 32) ^ ((kcol & 7) << 3))];
        sAcc[nt] = __builtin_amdgcn_mfma_f32_16x16x32_bf16(qf[ks], kf, sAcc[nt], 0, 0, 0);
      }

    float corr[4];
#pragma unroll
    for (int j = 0; j < 4; ++j) {
      int qg = q0 + w * 16 + g * 4 + j;
      float tm = -1e30f;
#pragma unroll
      for (int nt = 0; nt < 4; ++nt) {
        float s = sAcc[nt][j] * 0.125f;
        int tg = kbase + nt * 16 + fr;
        if (tg > qg) s = -1e30f;
        sAcc[nt][j] = s;
        tm = fmaxf(tm, s);
      }
      tm = fmaxf(tm, __shfl_xor(tm, 1, 16));
      tm = fmaxf(tm, __shfl_xor(tm, 2, 16));
      tm = fmaxf(tm, __shfl_xor(tm, 4, 16));
      tm = fmaxf(tm, __shfl_xor(tm, 8, 16));
      float mN = fmaxf(mRun[j], tm);
      corr[j] = __expf(mRun[j] - mN);
      mRun[j] = mN;
      float ps = 0.f;
#pragma unroll
      for (int nt = 0; nt < 4; ++nt) {
        float p = __expf(sAcc[nt][j] - mN);
        sAcc[nt][j] = p;
        ps += p;
      }
      ps += __shfl_xor(ps, 1, 16);
      ps += __shfl_xor(ps, 2, 16);
      ps += __shfl_xor(ps, 4, 16);
      ps += __shfl_xor(ps, 8, 16);
      lRun[j] = lRun[j] * corr[j] + ps;
    }

#pragma unroll
    for (int nt = 0; nt < 4; ++nt)
#pragma unroll
      for (int j = 0; j < 4; ++j) {
        int q = g * 4 + j;
        int t = nt * 16 + fr;
        Pw[q * 64 + (t ^ ((q & 7) << 3))] = f2bf(sAcc[nt][j]);
      }
#pragma unroll
    for (int nd = 0; nd < 4; ++nd)
#pragma unroll
      for (int j = 0; j < 4; ++j) oAcc[nd][j] *= corr[j];

#pragma unroll
    for (int ks = 0; ks < 2; ++ks) {
      short8 pf = *(const short8*)&Pw[fr * 64 + ((g * 8 + ks * 32) ^ ((fr & 7) << 3))];
#pragma unroll
      for (int nd = 0; nd < 4; ++nd) {
        int d = nd * 16 + fr;
        short8 vf = *(const short8*)&Vt[d * 64 + ((g * 8 + ks * 32) ^ ((fr & 7) << 3))];
        oAcc[nd] = __builtin_amdgcn_mfma_f32_16x16x32_bf16(pf, vf, oAcc[nd], 0, 0, 0);
      }
    }
  }

#pragma unroll
  for (int j = 0; j < 4; ++j) {
    float inv = 1.0f / lRun[j];
    int q = q0 + w * 16 + g * 4 + j;
    unsigned short* yr = y + (size_t)(b * Tlen + q) * Dm + h * HDm + fr;
#pragma unroll
    for (int nd = 0; nd < 4; ++nd)
      yr[nd * 16] = f2bf(oAcc[nd][j] * inv);
  }
}

extern "C" void kernel_launch(void* const* d_in, const int* in_sizes, int n_in,
                              void* d_out, int out_size, void* d_ws, size_t ws_size,
                              hipStream_t stream) {
  const int*   idx    = (const int*)d_in[0];
  const float* wte    = (const float*)d_in[1];
  const float* wpe    = (const float*)d_in[2];
  const float* ln1_w  = (const float*)d_in[3];
  const float* ln1_b  = (const float*)d_in[4];
  const float* attn_w = (const float*)d_in[5];
  const float* attn_b = (const float*)d_in[6];
  const float* proj_w = (const float*)d_in[7];
  const float* proj_b = (const float*)d_in[8];
  const float* ln2_w  = (const float*)d_in[9];
  const float* ln2_b  = (const float*)d_in[10];
  const float* fc_w   = (const float*)d_in[11];
  const float* fc_b   = (const float*)d_in[12];
  const float* fc2_w  = (const float*)d_in[13];
  const float* fc2_b  = (const float*)d_in[14];
  const float* lnf_w  = (const float*)d_in[15];
  const float* lnf_b  = (const float*)d_in[16];
  const float* lmw    = (const float*)d_in[17];
  float* out = (float*)d_out;

  float* x = (float*)d_ws;                                    // [M][768] fp32
  unsigned short* qkvb = (unsigned short*)(x + (size_t)Mrows * Dm);   // [M][2304] bf16
  unsigned short* xb   = qkvb + (size_t)Mrows * 3 * Dm;       // [M][768] bf16
  unsigned short* yb   = xb + (size_t)Mrows * Dm;             // [M][768] bf16
  unsigned short* mb   = yb + (size_t)Mrows * Dm;             // [M][3072] bf16
  unsigned short* wbuf = mb + (size_t)Mrows * 4 * Dm;         // weights region
  unsigned short* wAttn = wbuf;                               // [2304][768]
  unsigned short* wProj = wAttn + (size_t)3 * Dm * Dm;        // [768][768]
  unsigned short* wFc   = wProj + (size_t)Dm * Dm;            // [3072][768]
  unsigned short* wFc2  = wFc + (size_t)4 * Dm * Dm;          // [768][3072]

  // lm_head chunk size (multiple of 256, 256-row pad slack reserved); reuses wbuf
  const size_t baseBytes = (size_t)Mrows * Dm * 4 + (size_t)Mrows * 9 * Dm * 2;  // 34.6MB
  size_t availShorts = (ws_size - baseBytes) / 2;
  long long maxRows = (long long)(availShorts / Dm);
  long long cc = (maxRows - 256) & ~255LL;
  if (cc > Vv) cc = Vv;
  const int chunkCols = (int)cc;

  embed_kernel<<<(Mrows * Dm) / 1024, 256, 0, stream>>>(idx, wte, wpe, x);

  for (int l = 0; l < Ll; ++l) {
    tconv4_kernel<<<6912, 256, 0, stream>>>(
        attn_w + (size_t)l * Dm * 3 * Dm, proj_w + (size_t)l * Dm * Dm,
        fc_w + (size_t)l * Dm * 4 * Dm, fc2_w + (size_t)l * 4 * Dm * Dm,
        wAttn, wProj, wFc, wFc2);

    ln_wave<<<Mrows / 4, 256, 0, stream>>>(x, ln1_w + l * Dm, ln1_b + l * Dm, xb);
    gemm_bf16_sm<<<dim3(18, 32), 256, 0, stream>>>(xb, wAttn, Dm, attn_b + (size_t)l * 3 * Dm,
                                                   nullptr, qkvb, 3 * Dm, 0);
    attn_mfma<<<Bsz * Hh * 16, 256, 0, stream>>>(qkvb, yb);
    gemm_splitk<<<dim3(6, 32, 2), 256, 0, stream>>>(yb, wProj, Dm, Dm / 2,
                                                    proj_b + (size_t)l * Dm, x, Dm);
    ln_wave<<<Mrows / 4, 256, 0, stream>>>(x, ln2_w + l * Dm, ln2_b + l * Dm, xb);
    gemm_bf16_sm<<<dim3(24, 32), 256, 0, stream>>>(xb, wFc, Dm, fc_b + (size_t)l * 4 * Dm,
                                                   nullptr, mb, 4 * Dm, 1);
    gemm_splitk<<<dim3(6, 32, 2), 256, 0, stream>>>(mb, wFc2, 4 * Dm, 2 * Dm,
                                                    fc2_b + (size_t)l * Dm, x, Dm);
  }

  ln_wave<<<Mrows / 4, 256, 0, stream>>>(x, lnf_w, lnf_b, xb);
  for (int base = 0; base < Vv; base += chunkCols) {
    int ncv = Vv - base; if (ncv > chunkCols) ncv = chunkCols;
    int ntiles = (ncv + 255) / 256;
    // convert + zero-pad to full 256-col tiles (staging reads padded rows)
    tconv_kernel<<<dim3(ntiles * 8, 24), 256, 0, stream>>>(lmw + base, Vv, ncv, wbuf, Dm);
    int cpx = (ntiles + 7) / 8;
    gemm_big256<true><<<8 * 16 * cpx, 256, 0, stream>>>(
        xb, wbuf, Dm, out + base, Vv, ncv, ntiles);
  }
}